// Round 3
// baseline (374.305 us; speedup 1.0000x reference)
//
#include <hip/hip_runtime.h>
#include <hip/hip_bf16.h>

// Workspace layout (float indices)
#define OFF_COLSUM 0        // 64
#define OFF_S      64       // 4096
#define OFF_SHX    4160     // 64  (BN shift, xy head)
#define OFF_SHZ    4224     // 64
#define OFF_ACC    4288     // 8 loss accumulators
#define OFF_W1XS   4304     // ushort[4096] = 2048 floats (w1_xy^T * sc, bf16, [ch j][k])
#define OFF_W1ZS   6352     // ushort[4096]
#define OFF_WSEGS  8400     // ushort[2048] (w_seg^T bf16, [class j][k], rows 20..31 = 0)

typedef __attribute__((ext_vector_type(8))) short bf16x8;
typedef __attribute__((ext_vector_type(4))) float f32x4;

__device__ __forceinline__ unsigned short f2bfh(float x) {
    __hip_bfloat16 h = __float2bfloat16(x);   // RNE hw cvt
    return *reinterpret_cast<unsigned short*>(&h);
}

union BF8 { bf16x8 v; unsigned short u[8]; };

__device__ __forceinline__ void gload_lds16(const void* g, void* l) {
    __builtin_amdgcn_global_load_lds((const __attribute__((address_space(1))) void*)g,
                                     (__attribute__((address_space(3))) void*)l, 16, 0, 0);
}

// ---------------- Pass 1: colsum + S = F^T F via MFMA ----------------
// LDS tile transposed (channel-major) bf16 [64ch][72] (pad 8 -> 144B rows, b128-aligned,
// conflict-free frag reads: bank = 4*((l15+grp)%8), even 8-way spread).
__global__ __launch_bounds__(256) void k_stats(const float* __restrict__ feat,
                                               int N, int ntiles, int tpb,
                                               float* __restrict__ ws) {
    __shared__ __align__(16) unsigned short ftT[64 * 72];
    const int t = threadIdx.x;
    const int lane = t & 63, l15 = lane & 15, grp = lane >> 4, wv = t >> 6;
    const int q = t & 15;        // channel-quad handled in staging
    const f32x4 z4 = {0.f, 0.f, 0.f, 0.f};
    f32x4 acc[4] = {z4, z4, z4, z4};
    float cs4[4] = {0.f, 0.f, 0.f, 0.f};

    const int ti0 = blockIdx.x * tpb;
    const int tiend = min(ti0 + tpb, ntiles);

    for (int ti = ti0; ti < tiend; ++ti) {
        const int row0 = ti * 64;
        __syncthreads();
        // stage transposed: thread handles ch-quad q*4..+3, pt-pairs (t>>4) and 16+(t>>4)
#pragma unroll
        for (int u = 0; u < 2; u++) {
            const int pb = (t >> 4) + u * 16;          // pt-pair 0..31
            const int p0 = row0 + pb * 2;
            float4 f1 = make_float4(0.f, 0.f, 0.f, 0.f);
            float4 f2 = make_float4(0.f, 0.f, 0.f, 0.f);
            if (p0 < N)     f1 = *(const float4*)&feat[(size_t)p0 * 64 + q * 4];
            if (p0 + 1 < N) f2 = *(const float4*)&feat[(size_t)(p0 + 1) * 64 + q * 4];
            cs4[0] += f1.x + f2.x; cs4[1] += f1.y + f2.y;
            cs4[2] += f1.z + f2.z; cs4[3] += f1.w + f2.w;
            unsigned int* W = (unsigned int*)ftT;
            W[(q * 4 + 0) * 36 + pb] = (unsigned)f2bfh(f1.x) | ((unsigned)f2bfh(f2.x) << 16);
            W[(q * 4 + 1) * 36 + pb] = (unsigned)f2bfh(f1.y) | ((unsigned)f2bfh(f2.y) << 16);
            W[(q * 4 + 2) * 36 + pb] = (unsigned)f2bfh(f1.z) | ((unsigned)f2bfh(f2.z) << 16);
            W[(q * 4 + 3) * 36 + pb] = (unsigned)f2bfh(f1.w) | ((unsigned)f2bfh(f2.w) << 16);
        }
        __syncthreads();
        // A-frag: S-rows = wave's channels; B-frags: S-cols = nt channels; k = 64 points
        bf16x8 a0 = *(const bf16x8*)&ftT[(wv * 16 + l15) * 72 + grp * 8];
        bf16x8 a1 = *(const bf16x8*)&ftT[(wv * 16 + l15) * 72 + grp * 8 + 32];
#pragma unroll
        for (int nt = 0; nt < 4; nt++) {
            bf16x8 b0 = *(const bf16x8*)&ftT[(nt * 16 + l15) * 72 + grp * 8];
            bf16x8 b1 = *(const bf16x8*)&ftT[(nt * 16 + l15) * 72 + grp * 8 + 32];
            acc[nt] = __builtin_amdgcn_mfma_f32_16x16x32_bf16(a0, b0, acc[nt], 0, 0, 0);
            acc[nt] = __builtin_amdgcn_mfma_f32_16x16x32_bf16(a1, b1, acc[nt], 0, 0, 0);
        }
    }

    // S: D[row = 16wv + grp*4 + r][col = nt*16 + l15]
    float* S = ws + OFF_S;
#pragma unroll
    for (int nt = 0; nt < 4; nt++)
#pragma unroll
        for (int r = 0; r < 4; r++)
            atomicAdd(&S[(wv * 16 + grp * 4 + r) * 64 + nt * 16 + l15], acc[nt][r]);
    // colsum: reduce cs4 over grp (lanes sharing l15), grp0 atomically adds
#pragma unroll
    for (int c = 0; c < 4; c++) {
        float v = cs4[c];
        v += __shfl_xor(v, 16); v += __shfl_xor(v, 32);
        if (grp == 0) atomicAdd(&ws[OFF_COLSUM + q * 4 + c], v);
    }
}

// ------------- Prep: BN scale/shift; scaled bf16 weights -------------
__global__ __launch_bounds__(256) void k_prep(
    const float* __restrict__ w1xy, const float* __restrict__ b1xy,
    const float* __restrict__ gxy,  const float* __restrict__ bexy,
    const float* __restrict__ w1z,  const float* __restrict__ b1z,
    const float* __restrict__ gz,   const float* __restrict__ bez,
    const float* __restrict__ wseg, float Nf, float* __restrict__ ws) {
    __shared__ float S[64][64];
    __shared__ float cs[64];
    const int t = threadIdx.x;

    for (int i = t; i < 4096; i += 256) ((float*)S)[i] = ws[OFF_S + i];
    if (t < 64) cs[t] = ws[OFF_COLSUM + t];
    __syncthreads();

    if (t < 128) {
        const int head = t >> 6, j = t & 63;
        const float* w1 = head ? w1z : w1xy;
        float w[64];
#pragma unroll
        for (int k = 0; k < 64; k++) w[k] = w1[k * 64 + j];
        float d = 0.f;
#pragma unroll
        for (int k = 0; k < 64; k++) d = fmaf(cs[k], w[k], d);
        float quad = 0.f;
#pragma unroll
        for (int k = 0; k < 64; k++) {
            float rd = 0.f;
#pragma unroll
            for (int l = 0; l < 64; l++) rd = fmaf(S[k][l], w[l], rd);
            quad = fmaf(w[k], rd, quad);
        }
        const float b1 = head ? b1z[j] : b1xy[j];
        const float mu  = d / Nf + b1;
        const float eh2 = quad / Nf + 2.f * b1 * d / Nf + b1 * b1;
        const float var = eh2 - mu * mu;
        const float g  = head ? gz[j]  : gxy[j];
        const float be = head ? bez[j] : bexy[j];
        const float sc = g * rsqrtf(var + 1e-3f);
        const float sh = be - mu * sc;
        ws[(head ? OFF_SHZ : OFF_SHX) + j] = sh;
        unsigned short* dst = (unsigned short*)(ws + (head ? OFF_W1ZS : OFF_W1XS));
#pragma unroll
        for (int k = 0; k < 64; k++) dst[j * 64 + k] = f2bfh(w[k] * sc);
    } else if (t < 160) {
        const int j = t - 128;  // 0..31
        unsigned short* dst = (unsigned short*)(ws + OFF_WSEGS);
        for (int k = 0; k < 64; k++)
            dst[j * 64 + k] = (j < 20) ? f2bfh(wseg[k * 20 + j]) : (unsigned short)0;
    }
}

// ---------------- Pass 2: swapped-operand MFMA heads + lane-local tail ----------------
__global__ __launch_bounds__(256, 2) void k_loss(
    const float* __restrict__ feat, const float* __restrict__ coord,
    const int* __restrict__ seg, const int* __restrict__ inst,
    const float* __restrict__ cent,
    const unsigned short* __restrict__ w1xs, const unsigned short* __restrict__ w1zs,
    const unsigned short* __restrict__ wsegs,
    const float* __restrict__ shxv, const float* __restrict__ shzv,
    const float* __restrict__ w2xy, const float* __restrict__ b2xy,
    const float* __restrict__ w2z,  const float* __restrict__ b2z,
    const float* __restrict__ bseg,
    int N, int ntiles, int tpb, float* __restrict__ acc) {
    __shared__ __align__(16) float ftile[2][4096];   // 2 x 16KB fp32, linear units swizzled
    __shared__ float red[4][8];

    const int t = threadIdx.x;
    const int lane = t & 63, l15 = lane & 15, grp = lane >> 4, wv = t >> 6;

    // ---- loop-invariant: weight A-frags in VGPRs ----
    bf16x8 ax[4][2], az[4][2], ag[2][2];
#pragma unroll
    for (int nt = 0; nt < 4; nt++)
#pragma unroll
        for (int h = 0; h < 2; h++) {
            ax[nt][h] = *(const bf16x8*)&w1xs[(nt * 16 + l15) * 64 + grp * 8 + h * 32];
            az[nt][h] = *(const bf16x8*)&w1zs[(nt * 16 + l15) * 64 + grp * 8 + h * 32];
        }
#pragma unroll
    for (int nt = 0; nt < 2; nt++)
#pragma unroll
        for (int h = 0; h < 2; h++)
            ag[nt][h] = *(const bf16x8*)&wsegs[(nt * 16 + l15) * 64 + grp * 8 + h * 32];

    // ---- per-lane constants: channel c = nt*16 + grp*4 + r ----
    float shx_c[4][4], shz_c[4][4], w20[4][4], w21[4][4], w2zc[4][4], bs_c[2][4];
#pragma unroll
    for (int nt = 0; nt < 4; nt++)
#pragma unroll
        for (int r = 0; r < 4; r++) {
            const int c = nt * 16 + grp * 4 + r;
            shx_c[nt][r] = shxv[c]; shz_c[nt][r] = shzv[c];
            w20[nt][r] = w2xy[c * 2]; w21[nt][r] = w2xy[c * 2 + 1];
            w2zc[nt][r] = w2z[c];
        }
#pragma unroll
    for (int nt = 0; nt < 2; nt++)
#pragma unroll
        for (int r = 0; r < 4; r++) {
            const int c = nt * 16 + grp * 4 + r;
            bs_c[nt][r] = (c < 20) ? bseg[c] : -1e30f;
        }
    const float pb0 = b2xy[0], pb1 = b2xy[1], pbz = b2z[0];

    float s_nll = 0.f, s_vf = 0.f, s_l1xy = 0.f, s_cosxy = 0.f;
    float s_l1z = 0.f, s_cosz = 0.f, s_mask = 0.f;

    const int ti0 = blockIdx.x * tpb;
    const int tiend = min(ti0 + tpb, ntiles);

    // staging: linear 16B unit i holds feat[r=i>>4][4*((i&15)^(r&15)) ..+3]
    auto stage = [&](int bufi, int ti) {
        const int row0 = ti * 64;
        if (row0 + 64 <= N) {
#pragma unroll
            for (int c = 0; c < 4; c++) {
                const int r = (wv * 4 + c) * 4 + grp;
                const int u = l15 ^ (r & 15);
                gload_lds16(&feat[(size_t)(row0 + r) * 64 + u * 4],
                            &ftile[bufi][(wv * 4 + c) * 256]);
            }
        } else {
#pragma unroll
            for (int u2 = 0; u2 < 4; u2++) {
                const int i = t + u2 * 256;
                const int r = i >> 4, u = (i & 15) ^ (r & 15);
                float4 v = make_float4(0.f, 0.f, 0.f, 0.f);
                if (row0 + r < N) v = *(const float4*)&feat[(size_t)(row0 + r) * 64 + u * 4];
                *(float4*)&ftile[bufi][i * 4] = v;
            }
        }
    };

    if (ti0 < tiend) stage(0, ti0);
    int cur = 0;
    for (int ti = ti0; ti < tiend; ++ti) {
        __syncthreads();   // drains staging (vmcnt) -> ftile[cur] ready; prev reads done
        if (ti + 1 < tiend) stage(cur ^ 1, ti + 1);

        const int row0 = ti * 64;
        const int p = wv * 16 + l15;           // tile-local point (this lane's point)
        const int gp = row0 + p;
        const bool inb = (gp < N);
        const int tg = inb ? seg[gp] : -1;
        const int iv = inb ? inst[gp] : -1;
        float c0 = 0.f, c1 = 0.f, c2 = 0.f, e0 = 0.f, e1 = 0.f, e2 = 0.f;
        if (inb) {
            c0 = coord[(size_t)gp * 3]; c1 = coord[(size_t)gp * 3 + 1]; c2 = coord[(size_t)gp * 3 + 2];
            e0 = cent[(size_t)gp * 3];  e1 = cent[(size_t)gp * 3 + 1];  e2 = cent[(size_t)gp * 3 + 2];
        }

        // B-frag: this lane's point, k-octet = grp*8 (+32)
        const float* fb = ftile[cur];
        const float4 q0 = *(const float4*)&fb[(p * 16 + ((grp * 2)     ^ l15)) * 4];
        const float4 q1 = *(const float4*)&fb[(p * 16 + ((grp * 2 + 1) ^ l15)) * 4];
        const float4 q2 = *(const float4*)&fb[(p * 16 + ((8 + grp * 2) ^ l15)) * 4];
        const float4 q3 = *(const float4*)&fb[(p * 16 + ((9 + grp * 2) ^ l15)) * 4];
        BF8 b0, b1;
        b0.u[0] = f2bfh(q0.x); b0.u[1] = f2bfh(q0.y); b0.u[2] = f2bfh(q0.z); b0.u[3] = f2bfh(q0.w);
        b0.u[4] = f2bfh(q1.x); b0.u[5] = f2bfh(q1.y); b0.u[6] = f2bfh(q1.z); b0.u[7] = f2bfh(q1.w);
        b1.u[0] = f2bfh(q2.x); b1.u[1] = f2bfh(q2.y); b1.u[2] = f2bfh(q2.z); b1.u[3] = f2bfh(q2.w);
        b1.u[4] = f2bfh(q3.x); b1.u[5] = f2bfh(q3.y); b1.u[6] = f2bfh(q3.z); b1.u[7] = f2bfh(q3.w);

        // ---- seg head + CE ----
        f32x4 cg0 = {bs_c[0][0], bs_c[0][1], bs_c[0][2], bs_c[0][3]};
        cg0 = __builtin_amdgcn_mfma_f32_16x16x32_bf16(ag[0][0], b0.v, cg0, 0, 0, 0);
        cg0 = __builtin_amdgcn_mfma_f32_16x16x32_bf16(ag[0][1], b1.v, cg0, 0, 0, 0);
        f32x4 cg1 = {bs_c[1][0], bs_c[1][1], bs_c[1][2], bs_c[1][3]};
        cg1 = __builtin_amdgcn_mfma_f32_16x16x32_bf16(ag[1][0], b0.v, cg1, 0, 0, 0);
        cg1 = __builtin_amdgcn_mfma_f32_16x16x32_bf16(ag[1][1], b1.v, cg1, 0, 0, 0);
        float lmax = cg0[0];
#pragma unroll
        for (int r = 1; r < 4; r++) lmax = fmaxf(lmax, cg0[r]);
#pragma unroll
        for (int r = 0; r < 4; r++) lmax = fmaxf(lmax, cg1[r]);
        lmax = fmaxf(lmax, __shfl_xor(lmax, 16));
        lmax = fmaxf(lmax, __shfl_xor(lmax, 32));
        float se = 0.f;
#pragma unroll
        for (int r = 0; r < 4; r++) se += __expf(cg0[r] - lmax);
#pragma unroll
        for (int r = 0; r < 4; r++) se += __expf(cg1[r] - lmax);
        se += __shfl_xor(se, 16); se += __shfl_xor(se, 32);
        const float lse = lmax + __logf(se);
        float lt = 0.f;
#pragma unroll
        for (int r = 0; r < 4; r++) lt += (grp * 4 + r == tg) ? cg0[r] : 0.f;
#pragma unroll
        for (int r = 0; r < 4; r++) lt += (16 + grp * 4 + r == tg) ? cg1[r] : 0.f;
        lt += __shfl_xor(lt, 16); lt += __shfl_xor(lt, 32);
        const float vf = (tg >= 0) ? 1.f : 0.f;
        s_nll += (lse - lt) * vf;
        s_vf += vf;

        // ---- xy + z heads (scale folded into weights, shift via C-init) ----
        float s0 = 0.f, s1 = 0.f, szv = 0.f;
#pragma unroll
        for (int nt = 0; nt < 4; nt++) {
            f32x4 cc = {shx_c[nt][0], shx_c[nt][1], shx_c[nt][2], shx_c[nt][3]};
            cc = __builtin_amdgcn_mfma_f32_16x16x32_bf16(ax[nt][0], b0.v, cc, 0, 0, 0);
            cc = __builtin_amdgcn_mfma_f32_16x16x32_bf16(ax[nt][1], b1.v, cc, 0, 0, 0);
#pragma unroll
            for (int r = 0; r < 4; r++) {
                const float hx = fmaxf(cc[r], 0.f);
                s0 = fmaf(hx, w20[nt][r], s0);
                s1 = fmaf(hx, w21[nt][r], s1);
            }
            f32x4 cz = {shz_c[nt][0], shz_c[nt][1], shz_c[nt][2], shz_c[nt][3]};
            cz = __builtin_amdgcn_mfma_f32_16x16x32_bf16(az[nt][0], b0.v, cz, 0, 0, 0);
            cz = __builtin_amdgcn_mfma_f32_16x16x32_bf16(az[nt][1], b1.v, cz, 0, 0, 0);
#pragma unroll
            for (int r = 0; r < 4; r++) {
                const float hz = fmaxf(cz[r], 0.f);
                szv = fmaf(hz, w2zc[nt][r], szv);
            }
        }
        s0 += __shfl_xor(s0, 16);  s0 += __shfl_xor(s0, 32);
        s1 += __shfl_xor(s1, 16);  s1 += __shfl_xor(s1, 32);
        szv += __shfl_xor(szv, 16); szv += __shfl_xor(szv, 32);
        const float p0 = s0 + pb0, p1 = s1 + pb1, pz = szv + pbz;

        const float mk = (iv >= 0) ? 1.f : 0.f;
        const float a0 = e0 - c0, a1 = e1 - c1, a2 = e2 - c2;
        s_l1xy += (fabsf(a0 - p0) + fabsf(a1 - p1)) * mk;
        const float na = sqrtf(a0 * a0 + a1 * a1) + 1e-8f;
        const float nb = sqrtf(p0 * p0 + p1 * p1) + 1e-8f;
        s_cosxy -= ((a0 * p0 + a1 * p1) / (na * nb)) * mk;
        s_l1z += fabsf(a2 - pz) * mk;
        const float naz = fabsf(a2) + 1e-8f, nbz = fabsf(pz) + 1e-8f;
        s_cosz -= ((a2 * pz) / (naz * nbz)) * mk;
        s_mask += mk;

        cur ^= 1;
    }

    // block reduction; values replicated x4 across grp -> scale 0.25
    float v[7] = {s_nll * 0.25f, s_vf * 0.25f, s_l1xy * 0.25f, s_cosxy * 0.25f,
                  s_l1z * 0.25f, s_cosz * 0.25f, s_mask * 0.25f};
#pragma unroll
    for (int i = 0; i < 7; i++) {
#pragma unroll
        for (int o = 32; o > 0; o >>= 1) v[i] += __shfl_down(v[i], o);
    }
    if (lane == 0) {
#pragma unroll
        for (int i = 0; i < 7; i++) red[wv][i] = v[i];
    }
    __syncthreads();
    if (t < 7) {
        float s = red[0][t] + red[1][t] + red[2][t] + red[3][t];
        atomicAdd(&acc[t], s);
    }
}

// ---------------- Finalize ----------------
__global__ void k_fin(const float* __restrict__ acc, float* __restrict__ out) {
    const float sn = acc[0], sv = acc[1], sl1 = acc[2], scx = acc[3];
    const float slz = acc[4], scz_ = acc[5], sm = acc[6];
    const float segl = sn / sv;
    const float den = sm + 1e-8f;
    const float l1xy = sl1 / den, cosxy = scx / den;
    const float l1z = slz / den, cosz = scz_ / den;
    out[0] = segl + l1xy + l1xy + 0.5f * (l1z + cosz);
    out[1] = segl;
    out[2] = l1xy;
    out[3] = cosxy;
    out[4] = l1z;
    out[5] = cosz;
}

extern "C" void kernel_launch(void* const* d_in, const int* in_sizes, int n_in,
                              void* d_out, int out_size, void* d_ws, size_t ws_size,
                              hipStream_t stream) {
    const float* feat  = (const float*)d_in[0];
    const float* coord = (const float*)d_in[1];
    const int*   segm  = (const int*)d_in[2];
    const int*   inst  = (const int*)d_in[3];
    const float* cent  = (const float*)d_in[4];
    const float* w1xy  = (const float*)d_in[5];
    const float* b1xy  = (const float*)d_in[6];
    const float* gxy   = (const float*)d_in[7];
    const float* bexy  = (const float*)d_in[8];
    const float* w2xy  = (const float*)d_in[9];
    const float* b2xy  = (const float*)d_in[10];
    const float* w1z   = (const float*)d_in[11];
    const float* b1z   = (const float*)d_in[12];
    const float* gz    = (const float*)d_in[13];
    const float* bez   = (const float*)d_in[14];
    const float* w2z   = (const float*)d_in[15];
    const float* b2z   = (const float*)d_in[16];
    const float* wseg  = (const float*)d_in[17];
    const float* bseg  = (const float*)d_in[18];

    const int N = in_sizes[0] / 64;
    float* ws = (float*)d_ws;
    const int ntiles = (N + 63) >> 6;
    const int grid = 512;
    const int tpb = (ntiles + grid - 1) / grid;

    hipMemsetAsync(d_ws, 0, (OFF_S + 4096) * sizeof(float), stream);
    hipMemsetAsync((char*)d_ws + OFF_ACC * sizeof(float), 0, 8 * sizeof(float), stream);

    k_stats<<<grid, 256, 0, stream>>>(feat, N, ntiles, tpb, ws);
    k_prep<<<1, 256, 0, stream>>>(w1xy, b1xy, gxy, bexy, w1z, b1z, gz, bez, wseg,
                                  (float)N, ws);
    k_loss<<<grid, 256, 0, stream>>>(
        feat, coord, segm, inst, cent,
        (const unsigned short*)(ws + OFF_W1XS),
        (const unsigned short*)(ws + OFF_W1ZS),
        (const unsigned short*)(ws + OFF_WSEGS),
        ws + OFF_SHX, ws + OFF_SHZ,
        w2xy, b2xy, w2z, b2z, bseg, N, ntiles, tpb, ws + OFF_ACC);
    k_fin<<<1, 1, 0, stream>>>(ws + OFF_ACC, (float*)d_out);
}

// Round 4
// 176.299 us; speedup vs baseline: 2.1231x; 2.1231x over previous
//
#include <hip/hip_runtime.h>
#include <hip/hip_bf16.h>

// Workspace layout (float indices)
#define OFF_COLSUM 0        // 64
#define OFF_S      64       // 4096
#define OFF_SHX    4160     // 64  (BN shift, xy head)
#define OFF_SHZ    4224     // 64
#define OFF_ACC    4288     // 8 loss accumulators
#define OFF_W1XS   4304     // ushort[4096] (w1_xy^T * sc, bf16, [ch j][k])
#define OFF_W1ZS   6352     // ushort[4096]
#define OFF_WSEGS  8400     // ushort[2048] (w_seg^T bf16, rows 20..31 = 0)

typedef __attribute__((ext_vector_type(8))) short bf16x8;
typedef __attribute__((ext_vector_type(4))) float f32x4;

__device__ __forceinline__ unsigned short f2bfh(float x) {
    __hip_bfloat16 h = __float2bfloat16(x);
    return *reinterpret_cast<unsigned short*>(&h);
}

union BF8 { bf16x8 v; unsigned short u[8]; };

__device__ __forceinline__ void gload_lds16(const void* g, void* l) {
    __builtin_amdgcn_global_load_lds((const __attribute__((address_space(1))) void*)g,
                                     (__attribute__((address_space(3))) void*)l, 16, 0, 0);
}

// Shared staging layout (point-major, swizzled):
//   16B unit i of ftile holds feat[r = i>>4][4*((i&15) ^ (r&15)) .. +3]
//   word addr of F[p][c]:  p*64 + (((c>>2) ^ (p&15)) << 2) + (c&3)

// ---------------- Pass 1: colsum + S = F^T F via MFMA, column-frags ----------------
__global__ __launch_bounds__(256, 2) void k_stats(const float* __restrict__ feat,
                                                  int N, int ntiles, int tpb,
                                                  float* __restrict__ ws) {
    __shared__ __align__(16) float ftile[2][4096];
    const int t = threadIdx.x;
    const int lane = t & 63, l15 = lane & 15, grp = lane >> 4, wv = t >> 6;

    const f32x4 z4 = {0.f, 0.f, 0.f, 0.f};
    f32x4 acc[4] = {z4, z4, z4, z4};
    float csum = 0.f;

    const int l3 = l15 & 3;
    const int cb_base = l15 >> 2;   // c>>2 = g*4 + cb_base
    const int g1x8 = (grp & 1) * 8; // p&15 = g1x8 | kk

    const int ti0 = blockIdx.x * tpb;
    const int tiend = min(ti0 + tpb, ntiles);

    auto stage = [&](int bufi, int ti) {
        const int row0 = ti * 64;
        if (row0 + 64 <= N) {
#pragma unroll
            for (int c = 0; c < 4; c++) {
                const int r = (wv * 4 + c) * 4 + grp;
                const int u = l15 ^ (r & 15);
                gload_lds16(&feat[(size_t)(row0 + r) * 64 + u * 4],
                            &ftile[bufi][(wv * 4 + c) * 256]);
            }
        } else {
#pragma unroll
            for (int u2 = 0; u2 < 4; u2++) {
                const int i = t + u2 * 256;
                const int r = i >> 4, u = (i & 15) ^ (r & 15);
                float4 v = make_float4(0.f, 0.f, 0.f, 0.f);
                if (row0 + r < N) v = *(const float4*)&feat[(size_t)(row0 + r) * 64 + u * 4];
                *(float4*)&ftile[bufi][i * 4] = v;
            }
        }
    };

    if (ti0 < tiend) stage(0, ti0);
    int cur = 0;
    for (int ti = ti0; ti < tiend; ++ti) {
        __syncthreads();                      // drains staging vmcnt; prev reads done
        if (ti + 1 < tiend) stage(cur ^ 1, ti + 1);
        const float* fb = ftile[cur];

        // column frags: fr[s][h] lane(grp,l15) = F[h*32+grp*8+kk][g*16+l15], g=(wv+s)&3
        bf16x8 fr[4][2];
#pragma unroll
        for (int s = 0; s < 4; s++) {
            const int g = (wv + s) & 3;
            const int cb = (g * 4 + cb_base) ^ g1x8;
#pragma unroll
            for (int h = 0; h < 2; h++) {
                const int pbase = h * 32 + grp * 8;
                float vs[8];
#pragma unroll
                for (int kk = 0; kk < 8; kk++)
                    vs[kk] = fb[(pbase + kk) * 64 + ((cb ^ kk) << 2) + l3];
                BF8 fv;
#pragma unroll
                for (int kk = 0; kk < 8; kk++) fv.u[kk] = f2bfh(vs[kk]);
                fr[s][h] = fv.v;
                if (s == 0) {
#pragma unroll
                    for (int kk = 0; kk < 8; kk++) csum += vs[kk];
                }
            }
        }
        // D = F^T(g=wv rows) * F(g=(wv+s) cols); frag doubles as A and B
#pragma unroll
        for (int s = 0; s < 4; s++) {
            acc[s] = __builtin_amdgcn_mfma_f32_16x16x32_bf16(fr[0][0], fr[s][0], acc[s], 0, 0, 0);
            acc[s] = __builtin_amdgcn_mfma_f32_16x16x32_bf16(fr[0][1], fr[s][1], acc[s], 0, 0, 0);
        }
        cur ^= 1;
    }

    // S[row = wv*16 + grp*4 + r][col = ((wv+s)&3)*16 + l15]
    float* S = ws + OFF_S;
#pragma unroll
    for (int s = 0; s < 4; s++) {
        const int gj = (wv + s) & 3;
#pragma unroll
        for (int r = 0; r < 4; r++)
            atomicAdd(&S[(wv * 16 + grp * 4 + r) * 64 + gj * 16 + l15], acc[s][r]);
    }
    // colsum of channel wv*16 + l15: lane holds its grp's 16 points; reduce over grp
    csum += __shfl_xor(csum, 16);
    csum += __shfl_xor(csum, 32);
    if (grp == 0) atomicAdd(&ws[OFF_COLSUM + wv * 16 + l15], csum);
}

// ------------- Prep: BN scale/shift; scaled bf16 weights -------------
__global__ __launch_bounds__(256) void k_prep(
    const float* __restrict__ w1xy, const float* __restrict__ b1xy,
    const float* __restrict__ gxy,  const float* __restrict__ bexy,
    const float* __restrict__ w1z,  const float* __restrict__ b1z,
    const float* __restrict__ gz,   const float* __restrict__ bez,
    const float* __restrict__ wseg, float Nf, float* __restrict__ ws) {
    __shared__ float S[64][64];
    __shared__ float cs[64];
    const int t = threadIdx.x;

    for (int i = t; i < 4096; i += 256) ((float*)S)[i] = ws[OFF_S + i];
    if (t < 64) cs[t] = ws[OFF_COLSUM + t];
    __syncthreads();

    if (t < 128) {
        const int head = t >> 6, j = t & 63;
        const float* w1 = head ? w1z : w1xy;
        float w[64];
#pragma unroll
        for (int k = 0; k < 64; k++) w[k] = w1[k * 64 + j];
        float d = 0.f;
#pragma unroll
        for (int k = 0; k < 64; k++) d = fmaf(cs[k], w[k], d);
        float quad = 0.f;
#pragma unroll
        for (int k = 0; k < 64; k++) {
            float rd = 0.f;
#pragma unroll
            for (int l = 0; l < 64; l++) rd = fmaf(S[k][l], w[l], rd);
            quad = fmaf(w[k], rd, quad);
        }
        const float b1 = head ? b1z[j] : b1xy[j];
        const float mu  = d / Nf + b1;
        const float eh2 = quad / Nf + 2.f * b1 * d / Nf + b1 * b1;
        const float var = eh2 - mu * mu;
        const float g  = head ? gz[j]  : gxy[j];
        const float be = head ? bez[j] : bexy[j];
        const float sc = g * rsqrtf(var + 1e-3f);
        const float sh = be - mu * sc;
        ws[(head ? OFF_SHZ : OFF_SHX) + j] = sh;
        unsigned short* dst = (unsigned short*)(ws + (head ? OFF_W1ZS : OFF_W1XS));
#pragma unroll
        for (int k = 0; k < 64; k++) dst[j * 64 + k] = f2bfh(w[k] * sc);
    } else if (t < 160) {
        const int j = t - 128;  // 0..31
        unsigned short* dst = (unsigned short*)(ws + OFF_WSEGS);
        for (int k = 0; k < 64; k++)
            dst[j * 64 + k] = (j < 20) ? f2bfh(wseg[k * 20 + j]) : (unsigned short)0;
    }
}

// ---------------- Pass 2: swapped-operand MFMA heads + lane-local tail ----------------
__global__ __launch_bounds__(256, 2) void k_loss(
    const float* __restrict__ feat, const float* __restrict__ coord,
    const int* __restrict__ seg, const int* __restrict__ inst,
    const float* __restrict__ cent,
    const unsigned short* __restrict__ w1xs, const unsigned short* __restrict__ w1zs,
    const unsigned short* __restrict__ wsegs,
    const float* __restrict__ shxv, const float* __restrict__ shzv,
    const float* __restrict__ w2xy, const float* __restrict__ b2xy,
    const float* __restrict__ w2z,  const float* __restrict__ b2z,
    const float* __restrict__ bseg,
    int N, int ntiles, int tpb, float* __restrict__ acc) {
    __shared__ __align__(16) float ftile[2][4096];
    __shared__ float red[4][8];

    const int t = threadIdx.x;
    const int lane = t & 63, l15 = lane & 15, grp = lane >> 4, wv = t >> 6;

    // loop-invariant weight A-frags in VGPRs
    bf16x8 ax[4][2], az[4][2], ag[2][2];
#pragma unroll
    for (int nt = 0; nt < 4; nt++)
#pragma unroll
        for (int h = 0; h < 2; h++) {
            ax[nt][h] = *(const bf16x8*)&w1xs[(nt * 16 + l15) * 64 + grp * 8 + h * 32];
            az[nt][h] = *(const bf16x8*)&w1zs[(nt * 16 + l15) * 64 + grp * 8 + h * 32];
        }
#pragma unroll
    for (int nt = 0; nt < 2; nt++)
#pragma unroll
        for (int h = 0; h < 2; h++)
            ag[nt][h] = *(const bf16x8*)&wsegs[(nt * 16 + l15) * 64 + grp * 8 + h * 32];

    // per-lane constants: channel c = nt*16 + grp*4 + r
    float shx_c[4][4], shz_c[4][4], w20[4][4], w21[4][4], w2zc[4][4], bs_c[2][4];
#pragma unroll
    for (int nt = 0; nt < 4; nt++)
#pragma unroll
        for (int r = 0; r < 4; r++) {
            const int c = nt * 16 + grp * 4 + r;
            shx_c[nt][r] = shxv[c]; shz_c[nt][r] = shzv[c];
            w20[nt][r] = w2xy[c * 2]; w21[nt][r] = w2xy[c * 2 + 1];
            w2zc[nt][r] = w2z[c];
        }
#pragma unroll
    for (int nt = 0; nt < 2; nt++)
#pragma unroll
        for (int r = 0; r < 4; r++) {
            const int c = nt * 16 + grp * 4 + r;
            bs_c[nt][r] = (c < 20) ? bseg[c] : -1e30f;
        }
    const float pb0 = b2xy[0], pb1 = b2xy[1], pbz = b2z[0];

    float s_nll = 0.f, s_vf = 0.f, s_l1xy = 0.f, s_cosxy = 0.f;
    float s_l1z = 0.f, s_cosz = 0.f, s_mask = 0.f;

    const int ti0 = blockIdx.x * tpb;
    const int tiend = min(ti0 + tpb, ntiles);

    auto stage = [&](int bufi, int ti) {
        const int row0 = ti * 64;
        if (row0 + 64 <= N) {
#pragma unroll
            for (int c = 0; c < 4; c++) {
                const int r = (wv * 4 + c) * 4 + grp;
                const int u = l15 ^ (r & 15);
                gload_lds16(&feat[(size_t)(row0 + r) * 64 + u * 4],
                            &ftile[bufi][(wv * 4 + c) * 256]);
            }
        } else {
#pragma unroll
            for (int u2 = 0; u2 < 4; u2++) {
                const int i = t + u2 * 256;
                const int r = i >> 4, u = (i & 15) ^ (r & 15);
                float4 v = make_float4(0.f, 0.f, 0.f, 0.f);
                if (row0 + r < N) v = *(const float4*)&feat[(size_t)(row0 + r) * 64 + u * 4];
                *(float4*)&ftile[bufi][i * 4] = v;
            }
        }
    };

    // T14 prefetch: point-scalar data for tile ti loaded one iteration ahead
    int p_tg = -1, p_iv = -1;
    float p_c0 = 0.f, p_c1 = 0.f, p_c2 = 0.f, p_e0 = 0.f, p_e1 = 0.f, p_e2 = 0.f;
    auto ptload = [&](int ti) {
        const int gp = ti * 64 + wv * 16 + l15;
        const bool inb = (gp < N);
        p_tg = inb ? seg[gp] : -1;
        p_iv = inb ? inst[gp] : -1;
        if (inb) {
            p_c0 = coord[(size_t)gp * 3]; p_c1 = coord[(size_t)gp * 3 + 1]; p_c2 = coord[(size_t)gp * 3 + 2];
            p_e0 = cent[(size_t)gp * 3];  p_e1 = cent[(size_t)gp * 3 + 1];  p_e2 = cent[(size_t)gp * 3 + 2];
        } else {
            p_c0 = p_c1 = p_c2 = p_e0 = p_e1 = p_e2 = 0.f;
        }
    };

    if (ti0 < tiend) { stage(0, ti0); ptload(ti0); }
    int cur = 0;
    for (int ti = ti0; ti < tiend; ++ti) {
        // snapshot current tile's point data before prefetching next
        const int tg = p_tg, iv = p_iv;
        const float c0 = p_c0, c1 = p_c1, c2 = p_c2, e0 = p_e0, e1 = p_e1, e2 = p_e2;

        __syncthreads();   // ftile[cur] ready; prev reads done
        if (ti + 1 < tiend) { stage(cur ^ 1, ti + 1); ptload(ti + 1); }

        const int p = wv * 16 + l15;
        const float* fb = ftile[cur];
        const float4 q0 = *(const float4*)&fb[(p * 16 + ((grp * 2)     ^ l15)) * 4];
        const float4 q1 = *(const float4*)&fb[(p * 16 + ((grp * 2 + 1) ^ l15)) * 4];
        const float4 q2 = *(const float4*)&fb[(p * 16 + ((8 + grp * 2) ^ l15)) * 4];
        const float4 q3 = *(const float4*)&fb[(p * 16 + ((9 + grp * 2) ^ l15)) * 4];
        BF8 b0, b1;
        b0.u[0] = f2bfh(q0.x); b0.u[1] = f2bfh(q0.y); b0.u[2] = f2bfh(q0.z); b0.u[3] = f2bfh(q0.w);
        b0.u[4] = f2bfh(q1.x); b0.u[5] = f2bfh(q1.y); b0.u[6] = f2bfh(q1.z); b0.u[7] = f2bfh(q1.w);
        b1.u[0] = f2bfh(q2.x); b1.u[1] = f2bfh(q2.y); b1.u[2] = f2bfh(q2.z); b1.u[3] = f2bfh(q2.w);
        b1.u[4] = f2bfh(q3.x); b1.u[5] = f2bfh(q3.y); b1.u[6] = f2bfh(q3.z); b1.u[7] = f2bfh(q3.w);

        // ---- seg head + CE ----
        f32x4 cg0 = {bs_c[0][0], bs_c[0][1], bs_c[0][2], bs_c[0][3]};
        cg0 = __builtin_amdgcn_mfma_f32_16x16x32_bf16(ag[0][0], b0.v, cg0, 0, 0, 0);
        cg0 = __builtin_amdgcn_mfma_f32_16x16x32_bf16(ag[0][1], b1.v, cg0, 0, 0, 0);
        f32x4 cg1 = {bs_c[1][0], bs_c[1][1], bs_c[1][2], bs_c[1][3]};
        cg1 = __builtin_amdgcn_mfma_f32_16x16x32_bf16(ag[1][0], b0.v, cg1, 0, 0, 0);
        cg1 = __builtin_amdgcn_mfma_f32_16x16x32_bf16(ag[1][1], b1.v, cg1, 0, 0, 0);
        float lmax = cg0[0];
#pragma unroll
        for (int r = 1; r < 4; r++) lmax = fmaxf(lmax, cg0[r]);
#pragma unroll
        for (int r = 0; r < 4; r++) lmax = fmaxf(lmax, cg1[r]);
        lmax = fmaxf(lmax, __shfl_xor(lmax, 16));
        lmax = fmaxf(lmax, __shfl_xor(lmax, 32));
        float se = 0.f;
#pragma unroll
        for (int r = 0; r < 4; r++) se += __expf(cg0[r] - lmax);
#pragma unroll
        for (int r = 0; r < 4; r++) se += __expf(cg1[r] - lmax);
        se += __shfl_xor(se, 16); se += __shfl_xor(se, 32);
        const float lse = lmax + __logf(se);
        float lt = 0.f;
#pragma unroll
        for (int r = 0; r < 4; r++) lt += (grp * 4 + r == tg) ? cg0[r] : 0.f;
#pragma unroll
        for (int r = 0; r < 4; r++) lt += (16 + grp * 4 + r == tg) ? cg1[r] : 0.f;
        lt += __shfl_xor(lt, 16); lt += __shfl_xor(lt, 32);
        const float vf = (tg >= 0) ? 1.f : 0.f;
        s_nll += (lse - lt) * vf;
        s_vf += vf;

        // ---- xy + z heads ----
        float s0 = 0.f, s1 = 0.f, szv = 0.f;
#pragma unroll
        for (int nt = 0; nt < 4; nt++) {
            f32x4 cc = {shx_c[nt][0], shx_c[nt][1], shx_c[nt][2], shx_c[nt][3]};
            cc = __builtin_amdgcn_mfma_f32_16x16x32_bf16(ax[nt][0], b0.v, cc, 0, 0, 0);
            cc = __builtin_amdgcn_mfma_f32_16x16x32_bf16(ax[nt][1], b1.v, cc, 0, 0, 0);
#pragma unroll
            for (int r = 0; r < 4; r++) {
                const float hx = fmaxf(cc[r], 0.f);
                s0 = fmaf(hx, w20[nt][r], s0);
                s1 = fmaf(hx, w21[nt][r], s1);
            }
            f32x4 cz = {shz_c[nt][0], shz_c[nt][1], shz_c[nt][2], shz_c[nt][3]};
            cz = __builtin_amdgcn_mfma_f32_16x16x32_bf16(az[nt][0], b0.v, cz, 0, 0, 0);
            cz = __builtin_amdgcn_mfma_f32_16x16x32_bf16(az[nt][1], b1.v, cz, 0, 0, 0);
#pragma unroll
            for (int r = 0; r < 4; r++) {
                const float hz = fmaxf(cz[r], 0.f);
                szv = fmaf(hz, w2zc[nt][r], szv);
            }
        }
        s0 += __shfl_xor(s0, 16);  s0 += __shfl_xor(s0, 32);
        s1 += __shfl_xor(s1, 16);  s1 += __shfl_xor(s1, 32);
        szv += __shfl_xor(szv, 16); szv += __shfl_xor(szv, 32);
        const float p0 = s0 + pb0, p1 = s1 + pb1, pz = szv + pbz;

        const float mk = (iv >= 0) ? 1.f : 0.f;
        const float a0 = e0 - c0, a1 = e1 - c1, a2 = e2 - c2;
        s_l1xy += (fabsf(a0 - p0) + fabsf(a1 - p1)) * mk;
        const float na = sqrtf(a0 * a0 + a1 * a1) + 1e-8f;
        const float nb = sqrtf(p0 * p0 + p1 * p1) + 1e-8f;
        s_cosxy -= ((a0 * p0 + a1 * p1) / (na * nb)) * mk;
        s_l1z += fabsf(a2 - pz) * mk;
        const float naz = fabsf(a2) + 1e-8f, nbz = fabsf(pz) + 1e-8f;
        s_cosz -= ((a2 * pz) / (naz * nbz)) * mk;
        s_mask += mk;

        cur ^= 1;
    }

    // block reduction; values replicated x4 across grp -> scale 0.25
    float v[7] = {s_nll * 0.25f, s_vf * 0.25f, s_l1xy * 0.25f, s_cosxy * 0.25f,
                  s_l1z * 0.25f, s_cosz * 0.25f, s_mask * 0.25f};
#pragma unroll
    for (int i = 0; i < 7; i++) {
#pragma unroll
        for (int o = 32; o > 0; o >>= 1) v[i] += __shfl_down(v[i], o);
    }
    if (lane == 0) {
#pragma unroll
        for (int i = 0; i < 7; i++) red[wv][i] = v[i];
    }
    __syncthreads();
    if (t < 7) {
        float s = red[0][t] + red[1][t] + red[2][t] + red[3][t];
        atomicAdd(&acc[t], s);
    }
}

// ---------------- Finalize ----------------
__global__ void k_fin(const float* __restrict__ acc, float* __restrict__ out) {
    const float sn = acc[0], sv = acc[1], sl1 = acc[2], scx = acc[3];
    const float slz = acc[4], scz_ = acc[5], sm = acc[6];
    const float segl = sn / sv;
    const float den = sm + 1e-8f;
    const float l1xy = sl1 / den, cosxy = scx / den;
    const float l1z = slz / den, cosz = scz_ / den;
    out[0] = segl + l1xy + l1xy + 0.5f * (l1z + cosz);
    out[1] = segl;
    out[2] = l1xy;
    out[3] = cosxy;
    out[4] = l1z;
    out[5] = cosz;
}

extern "C" void kernel_launch(void* const* d_in, const int* in_sizes, int n_in,
                              void* d_out, int out_size, void* d_ws, size_t ws_size,
                              hipStream_t stream) {
    const float* feat  = (const float*)d_in[0];
    const float* coord = (const float*)d_in[1];
    const int*   segm  = (const int*)d_in[2];
    const int*   inst  = (const int*)d_in[3];
    const float* cent  = (const float*)d_in[4];
    const float* w1xy  = (const float*)d_in[5];
    const float* b1xy  = (const float*)d_in[6];
    const float* gxy   = (const float*)d_in[7];
    const float* bexy  = (const float*)d_in[8];
    const float* w2xy  = (const float*)d_in[9];
    const float* b2xy  = (const float*)d_in[10];
    const float* w1z   = (const float*)d_in[11];
    const float* b1z   = (const float*)d_in[12];
    const float* gz    = (const float*)d_in[13];
    const float* bez   = (const float*)d_in[14];
    const float* w2z   = (const float*)d_in[15];
    const float* b2z   = (const float*)d_in[16];
    const float* wseg  = (const float*)d_in[17];
    const float* bseg  = (const float*)d_in[18];

    const int N = in_sizes[0] / 64;
    float* ws = (float*)d_ws;
    const int ntiles = (N + 63) >> 6;
    const int grid = 512;
    const int tpb = (ntiles + grid - 1) / grid;

    hipMemsetAsync(d_ws, 0, (OFF_S + 4096) * sizeof(float), stream);
    hipMemsetAsync((char*)d_ws + OFF_ACC * sizeof(float), 0, 8 * sizeof(float), stream);

    k_stats<<<grid, 256, 0, stream>>>(feat, N, ntiles, tpb, ws);
    k_prep<<<1, 256, 0, stream>>>(w1xy, b1xy, gxy, bexy, w1z, b1z, gz, bez, wseg,
                                  (float)N, ws);
    k_loss<<<grid, 256, 0, stream>>>(
        feat, coord, segm, inst, cent,
        (const unsigned short*)(ws + OFF_W1XS),
        (const unsigned short*)(ws + OFF_W1ZS),
        (const unsigned short*)(ws + OFF_WSEGS),
        ws + OFF_SHX, ws + OFF_SHZ,
        w2xy, b2xy, w2z, b2z, bseg, N, ntiles, tpb, ws + OFF_ACC);
    k_fin<<<1, 1, 0, stream>>>(ws + OFF_ACC, (float*)d_out);
}